// Round 1
// baseline (12204.388 us; speedup 1.0000x reference)
//
#include <hip/hip_runtime.h>

#define UNROLL _Pragma("unroll")

typedef __attribute__((ext_vector_type(8))) short bf16x8;
typedef __attribute__((ext_vector_type(4))) float f32x4;

__device__ __forceinline__ unsigned short f2bf_rne(float x) {
  unsigned u = __float_as_uint(x);
  unsigned r = (u + 0x7FFFu + ((u >> 16) & 1u)) >> 16;
  return (unsigned short)r;
}

// ---------------- init: reset flags + h double-buffer ----------------
__global__ void k_init(unsigned* flags, float* hbuf) {
  int t = threadIdx.x;
  if (t < 64) flags[t] = 0u;
  for (int i = t; i < 1024; i += 256) hbuf[i] = 0.f;
}

// ---------------- persistent sequential LSTM (enc 512 + dec 511 steps) ----------------
// 64 blocks x 512 threads. Block owns hidden units [8b, 8b+8); wave w owns unit 8b+w.
// Lane l covers columns [8l, 8l+8) of both Wih and Whh rows (weights in registers).
// h double-buffered in global; per-block flag = number of steps published.
__global__ __launch_bounds__(512, 2) void k_lstm(
    const int* __restrict__ source, const int* __restrict__ target,
    const float* __restrict__ enc_embed, const float* __restrict__ enc_Wih,
    const float* __restrict__ enc_Whh, const float* __restrict__ enc_bih,
    const float* __restrict__ enc_bhh, const float* __restrict__ dec_embed,
    const float* __restrict__ dec_Wih, const float* __restrict__ dec_Whh,
    const float* __restrict__ dec_bih, const float* __restrict__ dec_bhh,
    unsigned* flags, float* hbuf, unsigned short* hsb) {
  const int blk = blockIdx.x;
  const int tid = threadIdx.x;
  const int lane = tid & 63;
  const int wv = tid >> 6;
  const int U = (blk << 3) + wv;  // global hidden unit

  __shared__ int toks[1024];
  toks[tid] = source[tid];
  toks[512 + tid] = target[tid];
  __syncthreads();

  float c = 0.f;
  int gs = 0;  // published global step count; h_gs lives in hbuf[gs&1]

  for (int phase = 0; phase < 2; ++phase) {
    const float* emb = phase ? dec_embed : enc_embed;
    const float* Wih = phase ? dec_Wih : enc_Wih;
    const float* Whh = phase ? dec_Whh : enc_Whh;
    const float* bih = phase ? dec_bih : enc_bih;
    const float* bhh = phase ? dec_bhh : enc_bhh;

    float wih[4][8], whh[4][8], bias[4];
    UNROLL for (int g = 0; g < 4; ++g) {
      const float* p1 = Wih + (size_t)((g << 9) + U) * 512 + (lane << 3);
      const float* p2 = Whh + (size_t)((g << 9) + U) * 512 + (lane << 3);
      UNROLL for (int k = 0; k < 8; ++k) { wih[g][k] = p1[k]; whh[g][k] = p2[k]; }
      bias[g] = bih[(g << 9) + U] + bhh[(g << 9) + U];
    }

    const int T = phase ? 511 : 512;
    const int tko = phase ? 512 : 0;
    for (int t = 0; t < T; ++t) {
      // embedding prefetch (independent of the recurrence -> issue before spin)
      const float* ep = emb + (size_t)toks[tko + t] * 512 + (lane << 3);
      float4 e0 = *(const float4*)ep;
      float4 e1 = *(const float4*)(ep + 4);

      // wait until every block has published step gs (lane l polls block l's flag)
      while (true) {
        unsigned f = __hip_atomic_load(&flags[lane], __ATOMIC_ACQUIRE, __HIP_MEMORY_SCOPE_AGENT);
        if (__all((int)(f >= (unsigned)gs))) break;
        __builtin_amdgcn_s_sleep(1);
      }

      const float* hp = hbuf + ((gs & 1) << 9) + (lane << 3);
      float4 h0 = *(const float4*)hp;
      float4 h1 = *(const float4*)(hp + 4);

      float ev[8] = {e0.x, e0.y, e0.z, e0.w, e1.x, e1.y, e1.z, e1.w};
      float hv[8] = {h0.x, h0.y, h0.z, h0.w, h1.x, h1.y, h1.z, h1.w};
      float acc[4];
      UNROLL for (int g = 0; g < 4; ++g) {
        float a = 0.f;
        UNROLL for (int k = 0; k < 8; ++k) a += wih[g][k] * ev[k];
        UNROLL for (int k = 0; k < 8; ++k) a += whh[g][k] * hv[k];
        acc[g] = a;
      }
      UNROLL for (int mask = 1; mask < 64; mask <<= 1) {
        UNROLL for (int g = 0; g < 4; ++g) acc[g] += __shfl_xor(acc[g], mask, 64);
      }
      // all lanes hold the full gate pre-activations for unit U
      float ia = 1.f / (1.f + expf(-(acc[0] + bias[0])));
      float fa = 1.f / (1.f + expf(-(acc[1] + bias[1])));
      float ga = tanhf(acc[2] + bias[2]);
      float oa = 1.f / (1.f + expf(-(acc[3] + bias[3])));
      c = fa * c + ia * ga;
      float h = oa * tanhf(c);
      gs++;
      if (lane == 0) {
        hbuf[((gs & 1) << 9) + U] = h;
        if (phase) hsb[((size_t)t << 9) + U] = f2bf_rne(h);  // decoder hs in bf16 for MFMA
      }
      __syncthreads();  // drains all waves' vmem stores before the release
      if (tid == 0)
        __hip_atomic_store(&flags[blk], (unsigned)gs, __ATOMIC_RELEASE, __HIP_MEMORY_SCOPE_AGENT);
    }
  }
}

// ---------------- logits GEMM (bf16 MFMA) + fused softmax partials ----------------
// grid (250, 4): 128 vocab cols x 128 t rows per block. 256 threads = 4 waves (2x2).
__global__ __launch_bounds__(256, 2) void k_logits(
    const unsigned short* __restrict__ hsb, const float* __restrict__ W_out,
    const float* __restrict__ b_out, const int* __restrict__ target,
    float* __restrict__ pmax, float* __restrict__ psum, float* __restrict__ tgt) {
  const int nt = blockIdx.x;
  const int mt = blockIdx.y;
  const int nbase = nt << 7;
  const int mbase = mt << 7;
  const int tid = threadIdx.x;
  const int l = tid & 63;
  const int q = l >> 4;
  const int cc = l & 15;
  const int W = tid >> 6;
  const int wm = W >> 1, wn = W & 1;

  __shared__ __align__(16) unsigned short Asm[128][40];  // +8 pad: bank spread
  __shared__ __align__(16) unsigned short Bsm[128][40];
  __shared__ float ex[2][128][2];

  f32x4 acc[4][4];
  f32x4 zero = {0.f, 0.f, 0.f, 0.f};
  UNROLL for (int i = 0; i < 4; ++i) UNROLL for (int j = 0; j < 4; ++j) acc[i][j] = zero;

  const int srow = tid >> 1;
  const int sh = tid & 1;

  for (int kc = 0; kc < 16; ++kc) {
    // stage A tile (bf16 hs rows)
    const unsigned short* ap = hsb + (size_t)(mbase + srow) * 512 + (kc << 5) + (sh << 4);
    uint4 a0 = *(const uint4*)ap;
    uint4 a1 = *(const uint4*)(ap + 8);
    *(uint4*)&Asm[srow][(sh << 4)] = a0;
    *(uint4*)&Asm[srow][(sh << 4) + 8] = a1;

    // stage B tile (f32 W_out rows -> bf16)
    const float* bp = W_out + (size_t)(nbase + srow) * 512 + (kc << 5) + (sh << 4);
    float bv[16];
    *(float4*)&bv[0] = *(const float4*)bp;
    *(float4*)&bv[4] = *(const float4*)(bp + 4);
    *(float4*)&bv[8] = *(const float4*)(bp + 8);
    *(float4*)&bv[12] = *(const float4*)(bp + 12);
    unsigned short us[16];
    UNROLL for (int j = 0; j < 16; ++j) us[j] = f2bf_rne(bv[j]);
    *(uint4*)&Bsm[srow][(sh << 4)] = *(const uint4*)&us[0];
    *(uint4*)&Bsm[srow][(sh << 4) + 8] = *(const uint4*)&us[8];

    __syncthreads();

    bf16x8 af[4], bfr[4];
    UNROLL for (int mi = 0; mi < 4; ++mi)
      af[mi] = *(const bf16x8*)((const char*)Asm + (size_t)((wm << 6) + (mi << 4) + cc) * 80 + (q << 4));
    UNROLL for (int ni = 0; ni < 4; ++ni)
      bfr[ni] = *(const bf16x8*)((const char*)Bsm + (size_t)((wn << 6) + (ni << 4) + cc) * 80 + (q << 4));
    UNROLL for (int mi = 0; mi < 4; ++mi)
      UNROLL for (int ni = 0; ni < 4; ++ni)
        acc[mi][ni] = __builtin_amdgcn_mfma_f32_16x16x32_bf16(af[mi], bfr[ni], acc[mi][ni], 0, 0, 0);

    __syncthreads();
  }

  // epilogue: + b_out; per-row (max, sumexp) over this block's 128 cols; target logit
  float bo[4];
  UNROLL for (int ni = 0; ni < 4; ++ni) bo[ni] = b_out[nbase + (wn << 6) + (ni << 4) + cc];
  UNROLL for (int mi = 0; mi < 4; ++mi)
    UNROLL for (int ni = 0; ni < 4; ++ni)
      UNROLL for (int r = 0; r < 4; ++r) acc[mi][ni][r] += bo[ni];

  UNROLL for (int mi = 0; mi < 4; ++mi) {
    UNROLL for (int r = 0; r < 4; ++r) {
      // C/D layout: col = lane&15, row = (lane>>4)*4 + r
      float v0 = acc[mi][0][r], v1 = acc[mi][1][r], v2 = acc[mi][2][r], v3 = acc[mi][3][r];
      float m = fmaxf(fmaxf(v0, v1), fmaxf(v2, v3));
      m = fmaxf(m, __shfl_xor(m, 1));
      m = fmaxf(m, __shfl_xor(m, 2));
      m = fmaxf(m, __shfl_xor(m, 4));
      m = fmaxf(m, __shfl_xor(m, 8));
      float s = __expf(v0 - m) + __expf(v1 - m) + __expf(v2 - m) + __expf(v3 - m);
      s += __shfl_xor(s, 1);
      s += __shfl_xor(s, 2);
      s += __shfl_xor(s, 4);
      s += __shfl_xor(s, 8);
      int rowb = (wm << 6) + (mi << 4) + (q << 2) + r;
      if (cc == 0) { ex[wn][rowb][0] = m; ex[wn][rowb][1] = s; }
      int t = mbase + rowb;
      if (t < 511) {
        int rel = target[t + 1] - nbase - (wn << 6);
        if (rel >= 0 && rel < 64 && (rel & 15) == cc) {
          int nisel = rel >> 4;
          float v = nisel == 0 ? v0 : (nisel == 1 ? v1 : (nisel == 2 ? v2 : v3));
          tgt[t] = v;
        }
      }
    }
  }
  __syncthreads();
  if (tid < 128) {
    int t = mbase + tid;
    if (t < 511) {
      float m0 = ex[0][tid][0], s0 = ex[0][tid][1];
      float m1 = ex[1][tid][0], s1 = ex[1][tid][1];
      float M = fmaxf(m0, m1);
      float S = s0 * __expf(m0 - M) + s1 * __expf(m1 - M);
      pmax[(nt << 9) + t] = M;
      psum[(nt << 9) + t] = S;
    }
  }
}

// ---------------- finalize: combine 250 partials per row ----------------
__global__ void k_loss(const float* __restrict__ pmax, const float* __restrict__ psum,
                       const float* __restrict__ tgt, float* __restrict__ out) {
  int t = threadIdx.x;
  if (t >= 511) return;
  float M = -3.4e38f;
  for (int nt = 0; nt < 250; ++nt) M = fmaxf(M, pmax[(nt << 9) + t]);
  float S = 0.f;
  for (int nt = 0; nt < 250; ++nt) S += psum[(nt << 9) + t] * __expf(pmax[(nt << 9) + t] - M);
  out[t] = M + logf(S) - tgt[t];
}

extern "C" void kernel_launch(void* const* d_in, const int* in_sizes, int n_in,
                              void* d_out, int out_size, void* d_ws, size_t ws_size,
                              hipStream_t stream) {
  const int* source = (const int*)d_in[0];
  const int* target = (const int*)d_in[1];
  const float* enc_embed = (const float*)d_in[2];
  const float* enc_Wih = (const float*)d_in[3];
  const float* enc_Whh = (const float*)d_in[4];
  const float* enc_bih = (const float*)d_in[5];
  const float* enc_bhh = (const float*)d_in[6];
  const float* dec_embed = (const float*)d_in[7];
  const float* dec_Wih = (const float*)d_in[8];
  const float* dec_Whh = (const float*)d_in[9];
  const float* dec_bih = (const float*)d_in[10];
  const float* dec_bhh = (const float*)d_in[11];
  const float* W_out = (const float*)d_in[12];
  const float* b_out = (const float*)d_in[13];
  float* out = (float*)d_out;

  char* ws = (char*)d_ws;
  unsigned* flags = (unsigned*)(ws);                    // 64 u32  @ 0
  float* hbuf = (float*)(ws + 1024);                    // 2*512 f32
  float* tgt = (float*)(ws + 5120);                     // 512 f32
  unsigned short* hsb = (unsigned short*)(ws + 7168);   // 512*512 bf16
  float* pmax = (float*)(ws + 531456);                  // 256*512 f32
  float* psum = (float*)(ws + 1055744);                 // 256*512 f32

  k_init<<<1, 256, 0, stream>>>(flags, hbuf);
  k_lstm<<<64, 512, 0, stream>>>(source, target, enc_embed, enc_Wih, enc_Whh, enc_bih, enc_bhh,
                                 dec_embed, dec_Wih, dec_Whh, dec_bih, dec_bhh, flags, hbuf, hsb);
  k_logits<<<dim3(250, 4), 256, 0, stream>>>(hsb, W_out, b_out, target, pmax, psum, tgt);
  k_loss<<<1, 512, 0, stream>>>(pmax, psum, tgt, out);
}

// Round 2
// 9421.954 us; speedup vs baseline: 1.2953x; 1.2953x over previous
//
#include <hip/hip_runtime.h>

#define UNROLL _Pragma("unroll")

typedef __attribute__((ext_vector_type(8))) short bf16x8;
typedef __attribute__((ext_vector_type(4))) float f32x4;

__device__ __forceinline__ unsigned short f2bf_rne(float x) {
  unsigned u = __float_as_uint(x);
  unsigned r = (u + 0x7FFFu + ((u >> 16) & 1u)) >> 16;
  return (unsigned short)r;
}

__device__ __forceinline__ float fast_sigmoid(float x) {
  return __builtin_amdgcn_rcpf(1.f + __expf(-x));
}
__device__ __forceinline__ float fast_tanh(float x) {
  return 1.f - 2.f * __builtin_amdgcn_rcpf(__expf(2.f * x) + 1.f);
}

// ---------------- init: reset tagged h-words (both parities) ----------------
__global__ void k_init(unsigned long long* hword) {
  int t = threadIdx.x;
  for (int i = t; i < 1024; i += 256) hword[i] = 0ull;  // tag=0, h=0
}

// ---------------- persistent sequential LSTM (enc 512 + dec 511 steps) ----------------
// 64 blocks x 512 threads. Block owns hidden units [8b, 8b+8); wave w owns unit 8b+w.
// Lane l covers columns [8l, 8l+8) of both Wih and Whh rows (weights pinned in VGPRs).
// h published per-unit as a tagged 64-bit word {tag=step, f32 h} with RELAXED agent
// atomics (single sc1 store / sc1 loads, no cache maintenance). Parity double-buffer.
__global__ __launch_bounds__(512, 1) void k_lstm(
    const int* __restrict__ source, const int* __restrict__ target,
    const float* __restrict__ enc_embed, const float* __restrict__ enc_Wih,
    const float* __restrict__ enc_Whh, const float* __restrict__ enc_bih,
    const float* __restrict__ enc_bhh, const float* __restrict__ dec_embed,
    const float* __restrict__ dec_Wih, const float* __restrict__ dec_Whh,
    const float* __restrict__ dec_bih, const float* __restrict__ dec_bhh,
    unsigned long long* hword, unsigned short* hsb) {
  const int blk = blockIdx.x;
  const int tid = threadIdx.x;
  const int lane = tid & 63;
  const int wv = tid >> 6;
  const int U = (blk << 3) + wv;  // global hidden unit

  __shared__ int toks[1024];
  toks[tid] = source[tid];
  toks[512 + tid] = target[tid];
  __syncthreads();

  float c = 0.f;

  for (int phase = 0; phase < 2; ++phase) {
    const float* emb = phase ? dec_embed : enc_embed;
    const float* Wih = phase ? dec_Wih : enc_Wih;
    const float* Whh = phase ? dec_Whh : enc_Whh;
    const float* bih = phase ? dec_bih : enc_bih;
    const float* bhh = phase ? dec_bhh : enc_bhh;

    float wih[4][8], whh[4][8], bias[4];
    UNROLL for (int g = 0; g < 4; ++g) {
      const float* p1 = Wih + (size_t)((g << 9) + U) * 512 + (lane << 3);
      const float* p2 = Whh + (size_t)((g << 9) + U) * 512 + (lane << 3);
      UNROLL for (int k = 0; k < 8; ++k) { wih[g][k] = p1[k]; whh[g][k] = p2[k]; }
      bias[g] = bih[(g << 9) + U] + bhh[(g << 9) + U];
    }
    // pin weights in VGPRs: forbid rematerialization / re-load inside the loop
    UNROLL for (int g = 0; g < 4; ++g) UNROLL for (int k = 0; k < 8; ++k) {
      asm volatile("" : "+v"(wih[g][k]));
      asm volatile("" : "+v"(whh[g][k]));
    }

    const int T = phase ? 511 : 512;
    const int tko = phase ? 512 : 0;
    for (int t = 0; t < T; ++t) {
      const int S = (phase ? 512 : 0) + t;  // global step: consume state-after-S-steps

      // embedding load + input-half of the dot product: independent of h
      const float* ep = emb + (size_t)toks[tko + t] * 512 + (lane << 3);
      float4 e0 = *(const float4*)ep;
      float4 e1 = *(const float4*)(ep + 4);
      float ev[8] = {e0.x, e0.y, e0.z, e0.w, e1.x, e1.y, e1.z, e1.w};
      float acc[4];
      UNROLL for (int g = 0; g < 4; ++g) {
        float a = 0.f;
        UNROLL for (int k = 0; k < 8; ++k) a += wih[g][k] * ev[k];
        acc[g] = a;
      }

      // gather h (tagged-word poll; lane l needs units 8l..8l+7)
      float hv[8];
      if (S == 0) {
        UNROLL for (int k = 0; k < 8; ++k) hv[k] = 0.f;
      } else {
        const unsigned long long* hw = hword + ((S & 1) << 9) + (lane << 3);
        while (true) {
          unsigned long long w[8];
          UNROLL for (int k = 0; k < 8; ++k)
            w[k] = __hip_atomic_load(&hw[k], __ATOMIC_RELAXED, __HIP_MEMORY_SCOPE_AGENT);
          bool ok = true;
          UNROLL for (int k = 0; k < 8; ++k) ok &= ((unsigned)(w[k] >> 32) == (unsigned)S);
          if (__all(ok)) {
            UNROLL for (int k = 0; k < 8; ++k) hv[k] = __uint_as_float((unsigned)w[k]);
            break;
          }
          __builtin_amdgcn_s_sleep(1);
        }
      }

      UNROLL for (int g = 0; g < 4; ++g) {
        float a = acc[g];
        UNROLL for (int k = 0; k < 8; ++k) a += whh[g][k] * hv[k];
        acc[g] = a;
      }
      UNROLL for (int mask = 1; mask < 64; mask <<= 1) {
        UNROLL for (int g = 0; g < 4; ++g) acc[g] += __shfl_xor(acc[g], mask, 64);
      }
      // all lanes hold full gate pre-activations for unit U
      float ia = fast_sigmoid(acc[0] + bias[0]);
      float fa = fast_sigmoid(acc[1] + bias[1]);
      float ga = fast_tanh(acc[2] + bias[2]);
      float oa = fast_sigmoid(acc[3] + bias[3]);
      c = fa * c + ia * ga;
      float h = oa * fast_tanh(c);

      if (lane == 0) {
        unsigned long long w =
            ((unsigned long long)(unsigned)(S + 1) << 32) | (unsigned long long)__float_as_uint(h);
        __hip_atomic_store(&hword[(((S + 1) & 1) << 9) + U], w, __ATOMIC_RELAXED,
                           __HIP_MEMORY_SCOPE_AGENT);
        if (phase) hsb[((size_t)t << 9) + U] = f2bf_rne(h);  // decoder hs in bf16 for MFMA
      }
    }
  }
}

// ---------------- logits GEMM (bf16 MFMA) + fused softmax partials ----------------
// grid (250, 4): 128 vocab cols x 128 t rows per block. 256 threads = 4 waves (2x2).
__global__ __launch_bounds__(256, 2) void k_logits(
    const unsigned short* __restrict__ hsb, const float* __restrict__ W_out,
    const float* __restrict__ b_out, const int* __restrict__ target,
    float* __restrict__ pmax, float* __restrict__ psum, float* __restrict__ tgt) {
  const int nt = blockIdx.x;
  const int mt = blockIdx.y;
  const int nbase = nt << 7;
  const int mbase = mt << 7;
  const int tid = threadIdx.x;
  const int l = tid & 63;
  const int q = l >> 4;
  const int cc = l & 15;
  const int W = tid >> 6;
  const int wm = W >> 1, wn = W & 1;

  __shared__ __align__(16) unsigned short Asm[128][40];  // +8 pad: bank spread
  __shared__ __align__(16) unsigned short Bsm[128][40];
  __shared__ float ex[2][128][2];

  f32x4 acc[4][4];
  f32x4 zero = {0.f, 0.f, 0.f, 0.f};
  UNROLL for (int i = 0; i < 4; ++i) UNROLL for (int j = 0; j < 4; ++j) acc[i][j] = zero;

  const int srow = tid >> 1;
  const int sh = tid & 1;

  for (int kc = 0; kc < 16; ++kc) {
    // stage A tile (bf16 hs rows)
    const unsigned short* ap = hsb + (size_t)(mbase + srow) * 512 + (kc << 5) + (sh << 4);
    uint4 a0 = *(const uint4*)ap;
    uint4 a1 = *(const uint4*)(ap + 8);
    *(uint4*)&Asm[srow][(sh << 4)] = a0;
    *(uint4*)&Asm[srow][(sh << 4) + 8] = a1;

    // stage B tile (f32 W_out rows -> bf16)
    const float* bp = W_out + (size_t)(nbase + srow) * 512 + (kc << 5) + (sh << 4);
    float bv[16];
    *(float4*)&bv[0] = *(const float4*)bp;
    *(float4*)&bv[4] = *(const float4*)(bp + 4);
    *(float4*)&bv[8] = *(const float4*)(bp + 8);
    *(float4*)&bv[12] = *(const float4*)(bp + 12);
    unsigned short us[16];
    UNROLL for (int j = 0; j < 16; ++j) us[j] = f2bf_rne(bv[j]);
    *(uint4*)&Bsm[srow][(sh << 4)] = *(const uint4*)&us[0];
    *(uint4*)&Bsm[srow][(sh << 4) + 8] = *(const uint4*)&us[8];

    __syncthreads();

    bf16x8 af[4], bfr[4];
    UNROLL for (int mi = 0; mi < 4; ++mi)
      af[mi] = *(const bf16x8*)((const char*)Asm + (size_t)((wm << 6) + (mi << 4) + cc) * 80 + (q << 4));
    UNROLL for (int ni = 0; ni < 4; ++ni)
      bfr[ni] = *(const bf16x8*)((const char*)Bsm + (size_t)((wn << 6) + (ni << 4) + cc) * 80 + (q << 4));
    UNROLL for (int mi = 0; mi < 4; ++mi)
      UNROLL for (int ni = 0; ni < 4; ++ni)
        acc[mi][ni] = __builtin_amdgcn_mfma_f32_16x16x32_bf16(af[mi], bfr[ni], acc[mi][ni], 0, 0, 0);

    __syncthreads();
  }

  // epilogue: + b_out; per-row (max, sumexp) over this block's 128 cols; target logit
  float bo[4];
  UNROLL for (int ni = 0; ni < 4; ++ni) bo[ni] = b_out[nbase + (wn << 6) + (ni << 4) + cc];
  UNROLL for (int mi = 0; mi < 4; ++mi)
    UNROLL for (int ni = 0; ni < 4; ++ni)
      UNROLL for (int r = 0; r < 4; ++r) acc[mi][ni][r] += bo[ni];

  UNROLL for (int mi = 0; mi < 4; ++mi) {
    UNROLL for (int r = 0; r < 4; ++r) {
      // C/D layout: col = lane&15, row = (lane>>4)*4 + r
      float v0 = acc[mi][0][r], v1 = acc[mi][1][r], v2 = acc[mi][2][r], v3 = acc[mi][3][r];
      float m = fmaxf(fmaxf(v0, v1), fmaxf(v2, v3));
      m = fmaxf(m, __shfl_xor(m, 1));
      m = fmaxf(m, __shfl_xor(m, 2));
      m = fmaxf(m, __shfl_xor(m, 4));
      m = fmaxf(m, __shfl_xor(m, 8));
      float s = __expf(v0 - m) + __expf(v1 - m) + __expf(v2 - m) + __expf(v3 - m);
      s += __shfl_xor(s, 1);
      s += __shfl_xor(s, 2);
      s += __shfl_xor(s, 4);
      s += __shfl_xor(s, 8);
      int rowb = (wm << 6) + (mi << 4) + (q << 2) + r;
      if (cc == 0) { ex[wn][rowb][0] = m; ex[wn][rowb][1] = s; }
      int t = mbase + rowb;
      if (t < 511) {
        int rel = target[t + 1] - nbase - (wn << 6);
        if (rel >= 0 && rel < 64 && (rel & 15) == cc) {
          int nisel = rel >> 4;
          float v = nisel == 0 ? v0 : (nisel == 1 ? v1 : (nisel == 2 ? v2 : v3));
          tgt[t] = v;
        }
      }
    }
  }
  __syncthreads();
  if (tid < 128) {
    int t = mbase + tid;
    if (t < 511) {
      float m0 = ex[0][tid][0], s0 = ex[0][tid][1];
      float m1 = ex[1][tid][0], s1 = ex[1][tid][1];
      float M = fmaxf(m0, m1);
      float S = s0 * __expf(m0 - M) + s1 * __expf(m1 - M);
      pmax[(nt << 9) + t] = M;
      psum[(nt << 9) + t] = S;
    }
  }
}

// ---------------- finalize: combine 250 partials per row ----------------
__global__ void k_loss(const float* __restrict__ pmax, const float* __restrict__ psum,
                       const float* __restrict__ tgt, float* __restrict__ out) {
  int t = threadIdx.x;
  if (t >= 511) return;
  float M = -3.4e38f;
  for (int nt = 0; nt < 250; ++nt) M = fmaxf(M, pmax[(nt << 9) + t]);
  float S = 0.f;
  for (int nt = 0; nt < 250; ++nt) S += psum[(nt << 9) + t] * __expf(pmax[(nt << 9) + t] - M);
  out[t] = M + logf(S) - tgt[t];
}

extern "C" void kernel_launch(void* const* d_in, const int* in_sizes, int n_in,
                              void* d_out, int out_size, void* d_ws, size_t ws_size,
                              hipStream_t stream) {
  const int* source = (const int*)d_in[0];
  const int* target = (const int*)d_in[1];
  const float* enc_embed = (const float*)d_in[2];
  const float* enc_Wih = (const float*)d_in[3];
  const float* enc_Whh = (const float*)d_in[4];
  const float* enc_bih = (const float*)d_in[5];
  const float* enc_bhh = (const float*)d_in[6];
  const float* dec_embed = (const float*)d_in[7];
  const float* dec_Wih = (const float*)d_in[8];
  const float* dec_Whh = (const float*)d_in[9];
  const float* dec_bih = (const float*)d_in[10];
  const float* dec_bhh = (const float*)d_in[11];
  const float* W_out = (const float*)d_in[12];
  const float* b_out = (const float*)d_in[13];
  float* out = (float*)d_out;

  char* ws = (char*)d_ws;
  unsigned long long* hword = (unsigned long long*)(ws);   // 2*512 u64 = 8192 B
  float* tgt = (float*)(ws + 8192);                        // 512 f32
  unsigned short* hsb = (unsigned short*)(ws + 10240);     // 512*512 bf16 = 512 KB
  float* pmax = (float*)(ws + 534528);                     // 250*512 f32 (stride 512)
  float* psum = (float*)(ws + 1058816);                    // 250*512 f32

  k_init<<<1, 256, 0, stream>>>(hword);
  k_lstm<<<64, 512, 0, stream>>>(source, target, enc_embed, enc_Wih, enc_Whh, enc_bih, enc_bhh,
                                 dec_embed, dec_Wih, dec_Whh, dec_bih, dec_bhh, hword, hsb);
  k_logits<<<dim3(250, 4), 256, 0, stream>>>(hsb, W_out, b_out, target, pmax, psum, tgt);
  k_loss<<<1, 512, 0, stream>>>(pmax, psum, tgt, out);
}

// Round 3
// 3070.338 us; speedup vs baseline: 3.9749x; 3.0687x over previous
//
#include <hip/hip_runtime.h>

#define UNROLL _Pragma("unroll")

typedef __attribute__((ext_vector_type(8))) short bf16x8;
typedef __attribute__((ext_vector_type(4))) float f32x4;

__device__ __forceinline__ unsigned short f2bf_rne(float x) {
  unsigned u = __float_as_uint(x);
  unsigned r = (u + 0x7FFFu + ((u >> 16) & 1u)) >> 16;
  return (unsigned short)r;
}

__device__ __forceinline__ float fast_sigmoid(float x) {
  return __builtin_amdgcn_rcpf(1.f + __expf(-x));
}
__device__ __forceinline__ float fast_tanh(float x) {
  return 1.f - 2.f * __builtin_amdgcn_rcpf(__expf(2.f * x) + 1.f);
}

// ---------------- init: reset tagged h-words (both parities) ----------------
__global__ void k_init(unsigned long long* hword) {
  int t = threadIdx.x;
  for (int i = t; i < 1024; i += 256) hword[i] = 0ull;  // tag=0, h=0
}

// ---------------- persistent sequential LSTM (enc 512 + dec 511 steps) ----------------
// 64 blocks x 512 threads (8 waves). Wave wv of block b computes unit U = 8b+wv.
// Weight columns are lane-strided by 64: lane l holds cols {l, 64+l, ..., 448+l}.
// h exchange: unit U's owner publishes a tagged u64 {tag=step, f32 h} via
// atomic_exchange (executes at coherence point). Wave wv of EVERY block polls only
// slice [64wv, 64wv+64) with ONE coalesced load, stages it to LDS, block-barriers,
// then all waves read the full h vector from LDS (stride-64, conflict-free).
__global__ __launch_bounds__(512, 1) void k_lstm(
    const int* __restrict__ source, const int* __restrict__ target,
    const float* __restrict__ enc_embed, const float* __restrict__ enc_Wih,
    const float* __restrict__ enc_Whh, const float* __restrict__ enc_bih,
    const float* __restrict__ enc_bhh, const float* __restrict__ dec_embed,
    const float* __restrict__ dec_Wih, const float* __restrict__ dec_Whh,
    const float* __restrict__ dec_bih, const float* __restrict__ dec_bhh,
    unsigned long long* hword, unsigned short* hsb) {
  const int blk = blockIdx.x;
  const int tid = threadIdx.x;
  const int lane = tid & 63;
  const int wv = tid >> 6;
  const int U = (blk << 3) + wv;  // global hidden unit

  __shared__ int toks[1024];
  __shared__ float hsm[512];
  toks[tid] = source[tid];
  toks[512 + tid] = target[tid];
  hsm[tid] = 0.f;
  __syncthreads();

  float c = 0.f;

  for (int phase = 0; phase < 2; ++phase) {
    const float* emb = phase ? dec_embed : enc_embed;
    const float* Wih = phase ? dec_Wih : enc_Wih;
    const float* Whh = phase ? dec_Whh : enc_Whh;
    const float* bih = phase ? dec_bih : enc_bih;
    const float* bhh = phase ? dec_bhh : enc_bhh;

    float wih[4][8], whh[4][8], bias[4];
    UNROLL for (int g = 0; g < 4; ++g) {
      const float* p1 = Wih + (size_t)((g << 9) + U) * 512 + lane;
      const float* p2 = Whh + (size_t)((g << 9) + U) * 512 + lane;
      UNROLL for (int k = 0; k < 8; ++k) { wih[g][k] = p1[k << 6]; whh[g][k] = p2[k << 6]; }
      bias[g] = bih[(g << 9) + U] + bhh[(g << 9) + U];
    }
    // pin weights in VGPRs (forbid re-load/remat inside the loop)
    UNROLL for (int g = 0; g < 4; ++g) UNROLL for (int k = 0; k < 8; ++k) {
      asm volatile("" : "+v"(wih[g][k]));
      asm volatile("" : "+v"(whh[g][k]));
    }

    const int T = phase ? 511 : 512;
    const int tko = phase ? 512 : 0;
    for (int t = 0; t < T; ++t) {
      const int S = (phase ? 512 : 0) + t;  // consume state-after-S-steps

      // embedding loads (coalesced dwords, stride-64); latency hides under the poll
      const float* ep = emb + (size_t)toks[tko + t] * 512 + lane;
      float ev[8];
      UNROLL for (int k = 0; k < 8; ++k) ev[k] = ep[k << 6];

      // wave wv polls ONLY its 64-unit slice: one coalesced 512B load per iteration
      if (S > 0) {
        const unsigned long long* hw = hword + ((S & 1) << 9) + (wv << 6) + lane;
        unsigned long long w;
        do {
          w = __hip_atomic_load(hw, __ATOMIC_RELAXED, __HIP_MEMORY_SCOPE_AGENT);
        } while (!__all((unsigned)(w >> 32) == (unsigned)S));
        hsm[(wv << 6) + lane] = __uint_as_float((unsigned)w);
      }
      __syncthreads();
      float hv[8];
      UNROLL for (int k = 0; k < 8; ++k) hv[k] = hsm[(k << 6) + lane];
      __syncthreads();  // reads done before next step's hsm writes

      float acc[4];
      UNROLL for (int g = 0; g < 4; ++g) {
        float a = 0.f;
        UNROLL for (int k = 0; k < 8; ++k) a += wih[g][k] * ev[k];
        UNROLL for (int k = 0; k < 8; ++k) a += whh[g][k] * hv[k];
        acc[g] = a;
      }
      UNROLL for (int mask = 1; mask < 64; mask <<= 1) {
        UNROLL for (int g = 0; g < 4; ++g) acc[g] += __shfl_xor(acc[g], mask, 64);
      }
      // all lanes hold full gate pre-activations for unit U
      float ia = fast_sigmoid(acc[0] + bias[0]);
      float fa = fast_sigmoid(acc[1] + bias[1]);
      float ga = fast_tanh(acc[2] + bias[2]);
      float oa = fast_sigmoid(acc[3] + bias[3]);
      c = fa * c + ia * ga;
      float h = oa * fast_tanh(c);

      if (lane == 0) {
        unsigned long long w =
            ((unsigned long long)(unsigned)(S + 1) << 32) | (unsigned long long)__float_as_uint(h);
        // RMW executes at the coherence point -> immediate agent-wide visibility
        (void)__hip_atomic_exchange(&hword[(((S + 1) & 1) << 9) + U], w, __ATOMIC_RELAXED,
                                    __HIP_MEMORY_SCOPE_AGENT);
        if (phase) hsb[((size_t)t << 9) + U] = f2bf_rne(h);  // decoder hs in bf16 for MFMA
      }
    }
  }
}

// ---------------- logits GEMM (bf16 MFMA) + fused softmax partials ----------------
// grid (250, 4): 128 vocab cols x 128 t rows per block. 256 threads = 4 waves (2x2).
__global__ __launch_bounds__(256, 2) void k_logits(
    const unsigned short* __restrict__ hsb, const float* __restrict__ W_out,
    const float* __restrict__ b_out, const int* __restrict__ target,
    float* __restrict__ pmax, float* __restrict__ psum, float* __restrict__ tgt) {
  const int nt = blockIdx.x;
  const int mt = blockIdx.y;
  const int nbase = nt << 7;
  const int mbase = mt << 7;
  const int tid = threadIdx.x;
  const int l = tid & 63;
  const int q = l >> 4;
  const int cc = l & 15;
  const int W = tid >> 6;
  const int wm = W >> 1, wn = W & 1;

  __shared__ __align__(16) unsigned short Asm[128][40];  // +8 pad: bank spread
  __shared__ __align__(16) unsigned short Bsm[128][40];
  __shared__ float ex[2][128][2];

  f32x4 acc[4][4];
  f32x4 zero = {0.f, 0.f, 0.f, 0.f};
  UNROLL for (int i = 0; i < 4; ++i) UNROLL for (int j = 0; j < 4; ++j) acc[i][j] = zero;

  const int srow = tid >> 1;
  const int sh = tid & 1;

  for (int kc = 0; kc < 16; ++kc) {
    // stage A tile (bf16 hs rows)
    const unsigned short* ap = hsb + (size_t)(mbase + srow) * 512 + (kc << 5) + (sh << 4);
    uint4 a0 = *(const uint4*)ap;
    uint4 a1 = *(const uint4*)(ap + 8);
    *(uint4*)&Asm[srow][(sh << 4)] = a0;
    *(uint4*)&Asm[srow][(sh << 4) + 8] = a1;

    // stage B tile (f32 W_out rows -> bf16)
    const float* bp = W_out + (size_t)(nbase + srow) * 512 + (kc << 5) + (sh << 4);
    float bv[16];
    *(float4*)&bv[0] = *(const float4*)bp;
    *(float4*)&bv[4] = *(const float4*)(bp + 4);
    *(float4*)&bv[8] = *(const float4*)(bp + 8);
    *(float4*)&bv[12] = *(const float4*)(bp + 12);
    unsigned short us[16];
    UNROLL for (int j = 0; j < 16; ++j) us[j] = f2bf_rne(bv[j]);
    *(uint4*)&Bsm[srow][(sh << 4)] = *(const uint4*)&us[0];
    *(uint4*)&Bsm[srow][(sh << 4) + 8] = *(const uint4*)&us[8];

    __syncthreads();

    bf16x8 af[4], bfr[4];
    UNROLL for (int mi = 0; mi < 4; ++mi)
      af[mi] = *(const bf16x8*)((const char*)Asm + (size_t)((wm << 6) + (mi << 4) + cc) * 80 + (q << 4));
    UNROLL for (int ni = 0; ni < 4; ++ni)
      bfr[ni] = *(const bf16x8*)((const char*)Bsm + (size_t)((wn << 6) + (ni << 4) + cc) * 80 + (q << 4));
    UNROLL for (int mi = 0; mi < 4; ++mi)
      UNROLL for (int ni = 0; ni < 4; ++ni)
        acc[mi][ni] = __builtin_amdgcn_mfma_f32_16x16x32_bf16(af[mi], bfr[ni], acc[mi][ni], 0, 0, 0);

    __syncthreads();
  }

  // epilogue: + b_out; per-row (max, sumexp) over this block's 128 cols; target logit
  float bo[4];
  UNROLL for (int ni = 0; ni < 4; ++ni) bo[ni] = b_out[nbase + (wn << 6) + (ni << 4) + cc];
  UNROLL for (int mi = 0; mi < 4; ++mi)
    UNROLL for (int ni = 0; ni < 4; ++ni)
      UNROLL for (int r = 0; r < 4; ++r) acc[mi][ni][r] += bo[ni];

  UNROLL for (int mi = 0; mi < 4; ++mi) {
    UNROLL for (int r = 0; r < 4; ++r) {
      // C/D layout: col = lane&15, row = (lane>>4)*4 + r
      float v0 = acc[mi][0][r], v1 = acc[mi][1][r], v2 = acc[mi][2][r], v3 = acc[mi][3][r];
      float m = fmaxf(fmaxf(v0, v1), fmaxf(v2, v3));
      m = fmaxf(m, __shfl_xor(m, 1));
      m = fmaxf(m, __shfl_xor(m, 2));
      m = fmaxf(m, __shfl_xor(m, 4));
      m = fmaxf(m, __shfl_xor(m, 8));
      float s = __expf(v0 - m) + __expf(v1 - m) + __expf(v2 - m) + __expf(v3 - m);
      s += __shfl_xor(s, 1);
      s += __shfl_xor(s, 2);
      s += __shfl_xor(s, 4);
      s += __shfl_xor(s, 8);
      int rowb = (wm << 6) + (mi << 4) + (q << 2) + r;
      if (cc == 0) { ex[wn][rowb][0] = m; ex[wn][rowb][1] = s; }
      int t = mbase + rowb;
      if (t < 511) {
        int rel = target[t + 1] - nbase - (wn << 6);
        if (rel >= 0 && rel < 64 && (rel & 15) == cc) {
          int nisel = rel >> 4;
          float v = nisel == 0 ? v0 : (nisel == 1 ? v1 : (nisel == 2 ? v2 : v3));
          tgt[t] = v;
        }
      }
    }
  }
  __syncthreads();
  if (tid < 128) {
    int t = mbase + tid;
    if (t < 511) {
      float m0 = ex[0][tid][0], s0 = ex[0][tid][1];
      float m1 = ex[1][tid][0], s1 = ex[1][tid][1];
      float M = fmaxf(m0, m1);
      float S = s0 * __expf(m0 - M) + s1 * __expf(m1 - M);
      pmax[(nt << 9) + t] = M;
      psum[(nt << 9) + t] = S;
    }
  }
}

// ---------------- finalize: combine 250 partials per row ----------------
__global__ void k_loss(const float* __restrict__ pmax, const float* __restrict__ psum,
                       const float* __restrict__ tgt, float* __restrict__ out) {
  int t = threadIdx.x;
  if (t >= 511) return;
  float M = -3.4e38f;
  for (int nt = 0; nt < 250; ++nt) M = fmaxf(M, pmax[(nt << 9) + t]);
  float S = 0.f;
  for (int nt = 0; nt < 250; ++nt) S += psum[(nt << 9) + t] * __expf(pmax[(nt << 9) + t] - M);
  out[t] = M + logf(S) - tgt[t];
}

extern "C" void kernel_launch(void* const* d_in, const int* in_sizes, int n_in,
                              void* d_out, int out_size, void* d_ws, size_t ws_size,
                              hipStream_t stream) {
  const int* source = (const int*)d_in[0];
  const int* target = (const int*)d_in[1];
  const float* enc_embed = (const float*)d_in[2];
  const float* enc_Wih = (const float*)d_in[3];
  const float* enc_Whh = (const float*)d_in[4];
  const float* enc_bih = (const float*)d_in[5];
  const float* enc_bhh = (const float*)d_in[6];
  const float* dec_embed = (const float*)d_in[7];
  const float* dec_Wih = (const float*)d_in[8];
  const float* dec_Whh = (const float*)d_in[9];
  const float* dec_bih = (const float*)d_in[10];
  const float* dec_bhh = (const float*)d_in[11];
  const float* W_out = (const float*)d_in[12];
  const float* b_out = (const float*)d_in[13];
  float* out = (float*)d_out;

  char* ws = (char*)d_ws;
  unsigned long long* hword = (unsigned long long*)(ws);   // 2*512 u64 = 8192 B
  float* tgt = (float*)(ws + 8192);                        // 512 f32
  unsigned short* hsb = (unsigned short*)(ws + 10240);     // 512*512 bf16 = 512 KB
  float* pmax = (float*)(ws + 534528);                     // 250*512 f32 (stride 512)
  float* psum = (float*)(ws + 1058816);                    // 250*512 f32

  k_init<<<1, 256, 0, stream>>>(hword);
  k_lstm<<<64, 512, 0, stream>>>(source, target, enc_embed, enc_Wih, enc_Whh, enc_bih, enc_bhh,
                                 dec_embed, dec_Wih, dec_Whh, dec_bih, dec_bhh, hword, hsb);
  k_logits<<<dim3(250, 4), 256, 0, stream>>>(hsb, W_out, b_out, target, pmax, psum, tgt);
  k_loss<<<1, 512, 0, stream>>>(pmax, psum, tgt, out);
}

// Round 5
// 1983.002 us; speedup vs baseline: 6.1545x; 1.5483x over previous
//
#include <hip/hip_runtime.h>

#define UNROLL _Pragma("unroll")

typedef __attribute__((ext_vector_type(8))) short bf16x8;
typedef __attribute__((ext_vector_type(4))) float f32x4;

__device__ __forceinline__ unsigned short f2bf_rne(float x) {
  unsigned u = __float_as_uint(x);
  unsigned r = (u + 0x7FFFu + ((u >> 16) & 1u)) >> 16;
  return (unsigned short)r;
}

__device__ __forceinline__ float fast_sigmoid(float x) {
  return __builtin_amdgcn_rcpf(1.f + __expf(-x));
}
__device__ __forceinline__ float fast_tanh(float x) {
  return 1.f - 2.f * __builtin_amdgcn_rcpf(__expf(2.f * x) + 1.f);
}

// ---------------- init: reset all 8 mailbox copies (tag=0) ----------------
__global__ void k_init(unsigned long long* hword) {
  int t = threadIdx.x;
  for (int i = t; i < 8192; i += 256) hword[i] = 0ull;  // 8 copies x 2 parities x 512
}

// ---------------- persistent sequential LSTM (enc 512 + dec 511 steps) ----------------
// 64 blocks x 512 threads (8 waves). Wave wv of block b computes unit U = 8b+wv.
// Weight columns lane-strided by 64 (coalesced); weights pinned in VGPRs.
// Publish: owner lane0 stores tagged u64 {tag=step, f32 h} to 8 REPLICATED mailboxes
// (relaxed agent atomics -> MALL). Block b polls ONLY copy b&7: per-line readers 64->8,
// poll address range spread 8KB->64KB across MALL channels. Tags ride inside the
// words; parity double-buffer; k_init re-zeroes -> replay safe.
__global__ __launch_bounds__(512, 1) void k_lstm(
    const int* __restrict__ source, const int* __restrict__ target,
    const float* __restrict__ enc_embed, const float* __restrict__ enc_Wih,
    const float* __restrict__ enc_Whh, const float* __restrict__ enc_bih,
    const float* __restrict__ enc_bhh, const float* __restrict__ dec_embed,
    const float* __restrict__ dec_Wih, const float* __restrict__ dec_Whh,
    const float* __restrict__ dec_bih, const float* __restrict__ dec_bhh,
    unsigned long long* hword, unsigned short* hsb) {
  const int blk = blockIdx.x;
  const int tid = threadIdx.x;
  const int lane = tid & 63;
  const int wv = tid >> 6;
  const int U = (blk << 3) + wv;      // global hidden unit
  const int mycopy = blk & 7;         // mailbox copy this block polls

  __shared__ int toks[1024];
  __shared__ float hsm[2][512];       // parity-split broadcast buffer (1 barrier/step)
  toks[tid] = source[tid];
  toks[512 + tid] = target[tid];
  __syncthreads();

  float c = 0.f;

  for (int phase = 0; phase < 2; ++phase) {
    const float* emb = phase ? dec_embed : enc_embed;
    const float* Wih = phase ? dec_Wih : enc_Wih;
    const float* Whh = phase ? dec_Whh : enc_Whh;
    const float* bih = phase ? dec_bih : enc_bih;
    const float* bhh = phase ? dec_bhh : enc_bhh;

    float wih[4][8], whh[4][8], bias[4];
    UNROLL for (int g = 0; g < 4; ++g) {
      const float* p1 = Wih + (size_t)((g << 9) + U) * 512 + lane;
      const float* p2 = Whh + (size_t)((g << 9) + U) * 512 + lane;
      UNROLL for (int k = 0; k < 8; ++k) { wih[g][k] = p1[k << 6]; whh[g][k] = p2[k << 6]; }
      bias[g] = bih[(g << 9) + U] + bhh[(g << 9) + U];
    }
    // pin weights in VGPRs (forbid re-load/remat inside the loop)
    UNROLL for (int g = 0; g < 4; ++g) UNROLL for (int k = 0; k < 8; ++k) {
      asm volatile("" : "+v"(wih[g][k]));
      asm volatile("" : "+v"(whh[g][k]));
    }

    const int T = phase ? 511 : 512;
    const int tko = phase ? 512 : 0;
    for (int t = 0; t < T; ++t) {
      const int S = (phase ? 512 : 0) + t;  // consume state-after-S-steps
      const int par = S & 1;

      // embedding loads (coalesced, stride-64) + input-half of dot product.
      // Computing acc now forces the embed vmcnt drain BEFORE the poll loop,
      // so the spin waits only on its own 512B poll load.
      const float* ep = emb + (size_t)toks[tko + t] * 512 + lane;
      float ev[8];
      UNROLL for (int k = 0; k < 8; ++k) ev[k] = ep[k << 6];
      float acc[4];
      UNROLL for (int g = 0; g < 4; ++g) {
        float a = 0.f;
        UNROLL for (int k = 0; k < 8; ++k) a += wih[g][k] * ev[k];
        acc[g] = a;
      }
      UNROLL for (int g = 0; g < 4; ++g) asm volatile("" : "+v"(acc[g]));  // don't sink past poll

      // wave wv polls its 64-unit slice of THIS block's mailbox copy
      if (S > 0) {
        const unsigned long long* hw = hword + (mycopy << 10) + (par << 9) + (wv << 6) + lane;
        unsigned long long w;
        do {
          w = __hip_atomic_load(hw, __ATOMIC_RELAXED, __HIP_MEMORY_SCOPE_AGENT);
        } while (!__all((unsigned)(w >> 32) == (unsigned)S));
        hsm[par][(wv << 6) + lane] = __uint_as_float((unsigned)w);
      }
      __syncthreads();
      float hv[8];
      if (S > 0) {
        UNROLL for (int k = 0; k < 8; ++k) hv[k] = hsm[par][(k << 6) + lane];
      } else {
        UNROLL for (int k = 0; k < 8; ++k) hv[k] = 0.f;
      }

      UNROLL for (int g = 0; g < 4; ++g) {
        float a = acc[g];
        UNROLL for (int k = 0; k < 8; ++k) a += whh[g][k] * hv[k];
        acc[g] = a;
      }
      UNROLL for (int mask = 1; mask < 64; mask <<= 1) {
        UNROLL for (int g = 0; g < 4; ++g) acc[g] += __shfl_xor(acc[g], mask, 64);
      }
      // all lanes hold full gate pre-activations for unit U
      float ia = fast_sigmoid(acc[0] + bias[0]);
      float fa = fast_sigmoid(acc[1] + bias[1]);
      float ga = fast_tanh(acc[2] + bias[2]);
      float oa = fast_sigmoid(acc[3] + bias[3]);
      c = fa * c + ia * ga;
      float h = oa * fast_tanh(c);

      if (lane == 0) {
        unsigned long long w =
            ((unsigned long long)(unsigned)(S + 1) << 32) | (unsigned long long)__float_as_uint(h);
        const int dst = (((S + 1) & 1) << 9) + U;
        UNROLL for (int cp = 0; cp < 8; ++cp)
          __hip_atomic_store(&hword[(cp << 10) + dst], w, __ATOMIC_RELAXED,
                             __HIP_MEMORY_SCOPE_AGENT);
        if (phase) hsb[((size_t)t << 9) + U] = f2bf_rne(h);  // decoder hs in bf16 for MFMA
      }
    }
  }
}

// ---------------- logits GEMM (bf16 MFMA) + fused softmax partials ----------------
// grid (250, 4): 128 vocab cols x 128 t rows per block. 256 threads = 4 waves (2x2).
__global__ __launch_bounds__(256, 2) void k_logits(
    const unsigned short* __restrict__ hsb, const float* __restrict__ W_out,
    const float* __restrict__ b_out, const int* __restrict__ target,
    float* __restrict__ pmax, float* __restrict__ psum, float* __restrict__ tgt) {
  const int nt = blockIdx.x;
  const int mt = blockIdx.y;
  const int nbase = nt << 7;
  const int mbase = mt << 7;
  const int tid = threadIdx.x;
  const int l = tid & 63;
  const int q = l >> 4;
  const int cc = l & 15;
  const int W = tid >> 6;
  const int wm = W >> 1, wn = W & 1;

  __shared__ __align__(16) unsigned short Asm[128][40];  // +8 pad: bank spread
  __shared__ __align__(16) unsigned short Bsm[128][40];
  __shared__ float ex[2][128][2];

  f32x4 acc[4][4];
  f32x4 zero = {0.f, 0.f, 0.f, 0.f};
  UNROLL for (int i = 0; i < 4; ++i) UNROLL for (int j = 0; j < 4; ++j) acc[i][j] = zero;

  const int srow = tid >> 1;
  const int sh = tid & 1;

  for (int kc = 0; kc < 16; ++kc) {
    // stage A tile (bf16 hs rows)
    const unsigned short* ap = hsb + (size_t)(mbase + srow) * 512 + (kc << 5) + (sh << 4);
    uint4 a0 = *(const uint4*)ap;
    uint4 a1 = *(const uint4*)(ap + 8);
    *(uint4*)&Asm[srow][(sh << 4)] = a0;
    *(uint4*)&Asm[srow][(sh << 4) + 8] = a1;

    // stage B tile (f32 W_out rows -> bf16)
    const float* bp = W_out + (size_t)(nbase + srow) * 512 + (kc << 5) + (sh << 4);
    float bv[16];
    *(float4*)&bv[0] = *(const float4*)bp;
    *(float4*)&bv[4] = *(const float4*)(bp + 4);
    *(float4*)&bv[8] = *(const float4*)(bp + 8);
    *(float4*)&bv[12] = *(const float4*)(bp + 12);
    unsigned short us[16];
    UNROLL for (int j = 0; j < 16; ++j) us[j] = f2bf_rne(bv[j]);
    *(uint4*)&Bsm[srow][(sh << 4)] = *(const uint4*)&us[0];
    *(uint4*)&Bsm[srow][(sh << 4) + 8] = *(const uint4*)&us[8];

    __syncthreads();

    bf16x8 af[4], bfr[4];
    UNROLL for (int mi = 0; mi < 4; ++mi)
      af[mi] = *(const bf16x8*)((const char*)Asm + (size_t)((wm << 6) + (mi << 4) + cc) * 80 + (q << 4));
    UNROLL for (int ni = 0; ni < 4; ++ni)
      bfr[ni] = *(const bf16x8*)((const char*)Bsm + (size_t)((wn << 6) + (ni << 4) + cc) * 80 + (q << 4));
    UNROLL for (int mi = 0; mi < 4; ++mi)
      UNROLL for (int ni = 0; ni < 4; ++ni)
        acc[mi][ni] = __builtin_amdgcn_mfma_f32_16x16x32_bf16(af[mi], bfr[ni], acc[mi][ni], 0, 0, 0);

    __syncthreads();
  }

  // epilogue: + b_out; per-row (max, sumexp) over this block's 128 cols; target logit
  float bo[4];
  UNROLL for (int ni = 0; ni < 4; ++ni) bo[ni] = b_out[nbase + (wn << 6) + (ni << 4) + cc];
  UNROLL for (int mi = 0; mi < 4; ++mi)
    UNROLL for (int ni = 0; ni < 4; ++ni)
      UNROLL for (int r = 0; r < 4; ++r) acc[mi][ni][r] += bo[ni];

  UNROLL for (int mi = 0; mi < 4; ++mi) {
    UNROLL for (int r = 0; r < 4; ++r) {
      // C/D layout: col = lane&15, row = (lane>>4)*4 + r
      float v0 = acc[mi][0][r], v1 = acc[mi][1][r], v2 = acc[mi][2][r], v3 = acc[mi][3][r];
      float m = fmaxf(fmaxf(v0, v1), fmaxf(v2, v3));
      m = fmaxf(m, __shfl_xor(m, 1));
      m = fmaxf(m, __shfl_xor(m, 2));
      m = fmaxf(m, __shfl_xor(m, 4));
      m = fmaxf(m, __shfl_xor(m, 8));
      float s = __expf(v0 - m) + __expf(v1 - m) + __expf(v2 - m) + __expf(v3 - m);
      s += __shfl_xor(s, 1);
      s += __shfl_xor(s, 2);
      s += __shfl_xor(s, 4);
      s += __shfl_xor(s, 8);
      int rowb = (wm << 6) + (mi << 4) + (q << 2) + r;
      if (cc == 0) { ex[wn][rowb][0] = m; ex[wn][rowb][1] = s; }
      int t = mbase + rowb;
      if (t < 511) {
        int rel = target[t + 1] - nbase - (wn << 6);
        if (rel >= 0 && rel < 64 && (rel & 15) == cc) {
          int nisel = rel >> 4;
          float v = nisel == 0 ? v0 : (nisel == 1 ? v1 : (nisel == 2 ? v2 : v3));
          tgt[t] = v;
        }
      }
    }
  }
  __syncthreads();
  if (tid < 128) {
    int t = mbase + tid;
    if (t < 511) {
      float m0 = ex[0][tid][0], s0 = ex[0][tid][1];
      float m1 = ex[1][tid][0], s1 = ex[1][tid][1];
      float M = fmaxf(m0, m1);
      float S = s0 * __expf(m0 - M) + s1 * __expf(m1 - M);
      pmax[(nt << 9) + t] = M;
      psum[(nt << 9) + t] = S;
    }
  }
}

// ---------------- finalize: combine 250 partials per row ----------------
__global__ void k_loss(const float* __restrict__ pmax, const float* __restrict__ psum,
                       const float* __restrict__ tgt, float* __restrict__ out) {
  int t = threadIdx.x;
  if (t >= 511) return;
  float M = -3.4e38f;
  for (int nt = 0; nt < 250; ++nt) M = fmaxf(M, pmax[(nt << 9) + t]);
  float S = 0.f;
  for (int nt = 0; nt < 250; ++nt) S += psum[(nt << 9) + t] * __expf(pmax[(nt << 9) + t] - M);
  out[t] = M + logf(S) - tgt[t];
}

extern "C" void kernel_launch(void* const* d_in, const int* in_sizes, int n_in,
                              void* d_out, int out_size, void* d_ws, size_t ws_size,
                              hipStream_t stream) {
  const int* source = (const int*)d_in[0];
  const int* target = (const int*)d_in[1];
  const float* enc_embed = (const float*)d_in[2];
  const float* enc_Wih = (const float*)d_in[3];
  const float* enc_Whh = (const float*)d_in[4];
  const float* enc_bih = (const float*)d_in[5];
  const float* enc_bhh = (const float*)d_in[6];
  const float* dec_embed = (const float*)d_in[7];
  const float* dec_Wih = (const float*)d_in[8];
  const float* dec_Whh = (const float*)d_in[9];
  const float* dec_bih = (const float*)d_in[10];
  const float* dec_bhh = (const float*)d_in[11];
  const float* W_out = (const float*)d_in[12];
  const float* b_out = (const float*)d_in[13];
  float* out = (float*)d_out;

  // Workspace map — byte-identical footprint to round 3 (proven).
  // hword (8 mailbox copies, 64 KB) aliases pmax: hword is live only during
  // k_lstm; pmax is written only by the later k_logits (stream-ordered, safe).
  char* ws = (char*)d_ws;
  unsigned long long* hword = (unsigned long long*)(ws + 16384);  // 8192 u64 = 64 KB
  float* pmax = (float*)(ws + 16384);                             // 250*512 f32 (aliases hword)
  float* tgt = (float*)(ws + 528384);                             // 512 f32
  unsigned short* hsb = (unsigned short*)(ws + 530432);           // 512*512 bf16 = 512 KB
  float* psum = (float*)(ws + 1054720);                           // 250*512 f32

  k_init<<<1, 256, 0, stream>>>(hword);
  k_lstm<<<64, 512, 0, stream>>>(source, target, enc_embed, enc_Wih, enc_Whh, enc_bih, enc_bhh,
                                 dec_embed, dec_Wih, dec_Whh, dec_bih, dec_bhh, hword, hsb);
  k_logits<<<dim3(250, 4), 256, 0, stream>>>(hsb, W_out, b_out, target, pmax, psum, tgt);
  k_loss<<<1, 512, 0, stream>>>(pmax, psum, tgt, out);
}